// Round 14
// baseline (29.365 us; speedup 1.0000x reference)
//
#include <hip/hip_runtime.h>

#define TPB 64          // one wave per block — wave-synchronous, no barriers

struct M3 { float a[9]; };
struct V3 { float x, y, z; };

__device__ __forceinline__ void fence_lgkm() {
    asm volatile("s_waitcnt lgkmcnt(0)" ::: "memory");
    __builtin_amdgcn_wave_barrier();
}

// rotation from 6 floats held in three float2s
__device__ __forceinline__ M3 rot6d2(float2 a, float2 b, float2 c) {
    float x0 = a.x, x1 = a.y, x2 = b.x;
    float y0 = b.y, y1 = c.x, y2 = c.y;
    float inx = rsqrtf(fmaxf(x0*x0 + x1*x1 + x2*x2, 1e-16f));
    x0 *= inx; x1 *= inx; x2 *= inx;
    float z0 = x1*y2 - x2*y1;
    float z1 = x2*y0 - x0*y2;
    float z2 = x0*y1 - x1*y0;
    float inz = rsqrtf(fmaxf(z0*z0 + z1*z1 + z2*z2, 1e-16f));
    z0 *= inz; z1 *= inz; z2 *= inz;
    float w0 = z1*x2 - z2*x1;
    float w1 = z2*x0 - z0*x2;
    float w2 = z0*x1 - z1*x0;
    M3 R;
    R.a[0] = x0; R.a[1] = w0; R.a[2] = z0;
    R.a[3] = x1; R.a[4] = w1; R.a[5] = z1;
    R.a[6] = x2; R.a[7] = w2; R.a[8] = z2;
    return R;
}

__device__ __forceinline__ M3 m3mul(const M3& A, const M3& B) {
    M3 C;
#pragma unroll
    for (int r = 0; r < 3; ++r)
#pragma unroll
        for (int c = 0; c < 3; ++c)
            C.a[3*r + c] = A.a[3*r + 0] * B.a[0 + c]
                         + A.a[3*r + 1] * B.a[3 + c]
                         + A.a[3*r + 2] * B.a[6 + c];
    return C;
}

__device__ __forceinline__ V3 step(const M3& P, V3 pp, int axis, float s) {
    V3 q;
    q.x = pp.x + s * P.a[0 + axis];
    q.y = pp.y + s * P.a[3 + axis];
    q.z = pp.z + s * P.a[6 + axis];
    return q;
}

__device__ __forceinline__ void put(float* so, int j, V3 q) {
    so[3*j + 0] = q.x; so[3*j + 1] = q.y; so[3*j + 2] = q.z;
}

// FK with operands read from the lane's LDS slice (vb = per-lane float2 base),
// results written to the s_out overlay slice `so`.
#define ROT(j) rot6d2(vb[3*(j)], vb[3*(j)+1], vb[3*(j)+2])
__device__ __forceinline__ void fk_from_lds(const float2* vb, float* so,
                                            const float* len,
                                            float rx, float ry, float rz) {
    V3 q0; q0.x = rx; q0.y = ry; q0.z = rz;
    so[0] = rx; so[1] = ry; so[2] = rz;
    M3 W0 = ROT(0);

    M3 W1 = m3mul(W0, ROT(1));   V3 q1 = step(W0, q0, 0, -len[0]);  put(so, 1, q1);
    M3 W2 = m3mul(W1, ROT(2));   V3 q2 = step(W1, q1, 1, -len[1]);  put(so, 2, q2);
    /* leaf 3 */                 V3 q3 = step(W2, q2, 1, -len[2]);  put(so, 3, q3);

    M3 W4 = m3mul(W0, ROT(4));   V3 q4 = step(W0, q0, 0,  len[3]);  put(so, 4, q4);
    M3 W5 = m3mul(W4, ROT(5));   V3 q5 = step(W4, q4, 1, -len[4]);  put(so, 5, q5);
    /* leaf 6 */                 V3 q6 = step(W5, q5, 1, -len[5]);  put(so, 6, q6);

    M3 W7 = m3mul(W0, ROT(7));   V3 q7 = step(W0, q0, 1,  len[6]);  put(so, 7, q7);
    M3 W8 = m3mul(W7, ROT(8));   V3 q8 = step(W7, q7, 1,  len[7]);  put(so, 8, q8);

    M3 W9 = m3mul(W8, ROT(9));   V3 q9 = step(W8, q8, 1,  len[8]);  put(so, 9, q9);
    /* leaf 10 */                V3 q10 = step(W9, q9, 1, len[9]);  put(so, 10, q10);

    M3 W11 = m3mul(W8,  ROT(11)); V3 q11 = step(W8,  q8,  0, len[10]); put(so, 11, q11);
    M3 W12 = m3mul(W11, ROT(12)); V3 q12 = step(W11, q11, 0, len[11]); put(so, 12, q12);
    /* leaf 13 */                 V3 q13 = step(W12, q12, 0, len[12]); put(so, 13, q13);

    M3 W14 = m3mul(W8,  ROT(14)); V3 q14 = step(W8,  q8,  0, -len[13]); put(so, 14, q14);
    M3 W15 = m3mul(W14, ROT(15)); V3 q15 = step(W14, q14, 0, -len[14]); put(so, 15, q15);
    /* leaf 16 */                 V3 q16 = step(W15, q15, 0, -len[15]); put(so, 16, q16);
}
#undef ROT

__global__ __launch_bounds__(TPB, 1) void PoseDecoder_kernel(
    const float* __restrict__ rot,    // [BL,17,6]
    const float* __restrict__ bones,  // [B,16]
    const float* __restrict__ root,   // [BL,3]
    float* __restrict__ out,          // [BL,17,3]
    int BL, int L)
{
    __shared__ __align__(16) float s_in[64 * 102];   // 26112 B input image
    __shared__ __align__(16) float s_out[64 * 51];   // 13056 B output overlay
    const int t = threadIdx.x;
    const long long blk_base = (long long)blockIdx.x * 128;

    const bool fast = (blk_base + 128 <= BL) &&
                      (blk_base / L == (blk_base + 127) / L);

    if (fast) {
        const long long b0 = blk_base, b1 = blk_base + 64;

        // ---- coalesced T0 loads -> regs (25 dwordx4 + 1 dwordx2) ----
        float4 g[25]; float2 gt;
        {
            const float4* g4 = (const float4*)(rot + (size_t)b0 * 102);
#pragma unroll
            for (int r = 0; r < 25; ++r) g[r] = g4[r * 64 + t];
            gt = ((const float2*)(rot + (size_t)b0 * 102 + 6400))[t];
        }
        // roots for both tiles (small scattered loads, in flight early)
        const long long gA = b0 + t, gB = b1 + t;
        float rAx = root[gA*3+0], rAy = root[gA*3+1], rAz = root[gA*3+2];
        float rBx = root[gB*3+0], rBy = root[gB*3+1], rBz = root[gB*3+2];
        // bones scalar (one group per 128-sample block; L multiple of 128)
        const float* bl = bones + (size_t)(blk_base / L) * 16;
        float len[16];
#pragma unroll
        for (int k = 0; k < 16; ++k) len[k] = bl[k];

        // ---- T0 stage to LDS (compiler inserts counted vmcnt per reg) ----
        {
            float4* l4 = (float4*)s_in;
#pragma unroll
            for (int r = 0; r < 25; ++r) l4[r * 64 + t] = g[r];
            ((float2*)(s_in + 6400))[t] = gt;
        }
        // ---- issue T1 coalesced loads (reuse g; WAR orders after ds_writes) ----
        {
            const float4* g4 = (const float4*)(rot + (size_t)b1 * 102);
#pragma unroll
            for (int r = 0; r < 25; ++r) g[r] = g4[r * 64 + t];
            gt = ((const float2*)(rot + (size_t)b1 * 102 + 6400))[t];
        }
        fence_lgkm();                    // T0 image visible to the wave

        // ---- FK T0 out of LDS (T1 loads flying underneath) ----
        fk_from_lds((const float2*)s_in + t * 51, s_out + t * 51, len, rAx, rAy, rAz);
        fence_lgkm();                    // overlay complete

        // ---- coalesced store T0 ----
        {
            float4* o4 = (float4*)(out + (size_t)b0 * 51);
            const float4* l4 = (const float4*)s_out;
#pragma unroll
            for (int r = 0; r < 12; ++r) o4[r * 64 + t] = l4[r * 64 + t];
            if (t < 48) o4[768 + t] = l4[768 + t];
        }
        fence_lgkm();                    // store's ds_reads retired; s_out reusable

        // ---- T1 stage to LDS (loads landed under FK T0) ----
        {
            float4* l4 = (float4*)s_in;
#pragma unroll
            for (int r = 0; r < 25; ++r) l4[r * 64 + t] = g[r];
            ((float2*)(s_in + 6400))[t] = gt;
        }
        fence_lgkm();                    // T1 image visible

        // ---- FK T1 + store ----
        fk_from_lds((const float2*)s_in + t * 51, s_out + t * 51, len, rBx, rBy, rBz);
        fence_lgkm();
        {
            float4* o4 = (float4*)(out + (size_t)b1 * 51);
            const float4* l4 = (const float4*)s_out;
#pragma unroll
            for (int r = 0; r < 12; ++r) o4[r * 64 + t] = l4[r * 64 + t];
            if (t < 48) o4[768 + t] = l4[768 + t];
        }
    } else {
        // generic fallback (partial block / bone-boundary crossing): per-sample
        // scattered path. Unused at BL=131072, L=256.
        for (int half = 0; half < 2; ++half) {
            const long long gs = blk_base + half * 64 + t;
            if (gs >= BL) break;
            const float2* g2 = (const float2*)(rot + (size_t)gs * 102);
            float2 vbuf[36];
            constexpr int UJ[12] = {0,1,2,4,5,7,8,9,11,12,14,15};
#pragma unroll
            for (int u = 0; u < 12; ++u)
#pragma unroll
                for (int k = 0; k < 3; ++k) vbuf[u*3+k] = g2[UJ[u]*3 + k];
            float rx = root[gs*3+0], ry = root[gs*3+1], rz = root[gs*3+2];
            const float* bl = bones + (size_t)(gs / L) * 16;
            float len[16];
#pragma unroll
            for (int k = 0; k < 16; ++k) len[k] = bl[k];
            // remap to joint-indexed reads for fk_from_lds-style access
            float so[51];
            {
                // inline FK using vbuf in UJ order
                auto R = [&](int u){ return rot6d2(vbuf[u*3], vbuf[u*3+1], vbuf[u*3+2]); };
                V3 q0{rx, ry, rz};
                so[0]=rx; so[1]=ry; so[2]=rz;
                M3 W0 = R(0);
                M3 W1 = m3mul(W0, R(1));   V3 q1 = step(W0, q0, 0, -len[0]);  put(so,1,q1);
                M3 W2 = m3mul(W1, R(2));   V3 q2 = step(W1, q1, 1, -len[1]);  put(so,2,q2);
                V3 q3 = step(W2, q2, 1, -len[2]);  put(so,3,q3);
                M3 W4 = m3mul(W0, R(3));   V3 q4 = step(W0, q0, 0,  len[3]);  put(so,4,q4);
                M3 W5 = m3mul(W4, R(4));   V3 q5 = step(W4, q4, 1, -len[4]);  put(so,5,q5);
                V3 q6 = step(W5, q5, 1, -len[5]);  put(so,6,q6);
                M3 W7 = m3mul(W0, R(5));   V3 q7 = step(W0, q0, 1,  len[6]);  put(so,7,q7);
                M3 W8 = m3mul(W7, R(6));   V3 q8 = step(W7, q7, 1,  len[7]);  put(so,8,q8);
                M3 W9 = m3mul(W8, R(7));   V3 q9 = step(W8, q8, 1,  len[8]);  put(so,9,q9);
                V3 q10 = step(W9, q9, 1, len[9]);  put(so,10,q10);
                M3 W11 = m3mul(W8,  R(8));  V3 q11 = step(W8,  q8,  0, len[10]); put(so,11,q11);
                M3 W12 = m3mul(W11, R(9));  V3 q12 = step(W11, q11, 0, len[11]); put(so,12,q12);
                V3 q13 = step(W12, q12, 0, len[12]); put(so,13,q13);
                M3 W14 = m3mul(W8,  R(10)); V3 q14 = step(W8,  q8,  0, -len[13]); put(so,14,q14);
                M3 W15 = m3mul(W14, R(11)); V3 q15 = step(W14, q14, 0, -len[14]); put(so,15,q15);
                V3 q16 = step(W15, q15, 0, -len[15]); put(so,16,q16);
            }
            for (int m = 0; m < 51; ++m) out[gs * 51 + m] = so[m];
        }
    }
}

extern "C" void kernel_launch(void* const* d_in, const int* in_sizes, int n_in,
                              void* d_out, int out_size, void* d_ws, size_t ws_size,
                              hipStream_t stream) {
    const float* rot   = (const float*)d_in[0];
    const float* bones = (const float*)d_in[1];
    const float* root  = (const float*)d_in[2];
    float* out = (float*)d_out;

    int BL = in_sizes[0] / 102;     // 17 joints * 6
    int B  = in_sizes[1] / 16;      // 16 bones
    int L  = BL / B;

    int grid = (BL + 127) / 128;
    PoseDecoder_kernel<<<grid, TPB, 0, stream>>>(rot, bones, root, out, BL, L);
}

// Round 15
// 20.809 us; speedup vs baseline: 1.4112x; 1.4112x over previous
//
#include <hip/hip_runtime.h>

#define TPB 64          // one wave per block — wave-synchronous, no barriers

typedef const __attribute__((address_space(1))) void g_void;
typedef __attribute__((address_space(3))) void lds_void;

struct M3 { float a[9]; };
struct V3 { float x, y, z; };

__device__ __forceinline__ void fence_lgkm() {
    asm volatile("s_waitcnt lgkmcnt(0)" ::: "memory");
    __builtin_amdgcn_wave_barrier();
}

// rotation from 6 floats held in three float2 registers
__device__ __forceinline__ M3 rot6d2(const float2* v) {
    float x0 = v[0].x, x1 = v[0].y, x2 = v[1].x;
    float y0 = v[1].y, y1 = v[2].x, y2 = v[2].y;
    float inx = rsqrtf(fmaxf(x0*x0 + x1*x1 + x2*x2, 1e-16f));
    x0 *= inx; x1 *= inx; x2 *= inx;
    float z0 = x1*y2 - x2*y1;
    float z1 = x2*y0 - x0*y2;
    float z2 = x0*y1 - x1*y0;
    float inz = rsqrtf(fmaxf(z0*z0 + z1*z1 + z2*z2, 1e-16f));
    z0 *= inz; z1 *= inz; z2 *= inz;
    float w0 = z1*x2 - z2*x1;
    float w1 = z2*x0 - z0*x2;
    float w2 = z0*x1 - z1*x0;
    M3 R;
    R.a[0] = x0; R.a[1] = w0; R.a[2] = z0;
    R.a[3] = x1; R.a[4] = w1; R.a[5] = z1;
    R.a[6] = x2; R.a[7] = w2; R.a[8] = z2;
    return R;
}

__device__ __forceinline__ M3 m3mul(const M3& A, const M3& B) {
    M3 C;
#pragma unroll
    for (int r = 0; r < 3; ++r)
#pragma unroll
        for (int c = 0; c < 3; ++c)
            C.a[3*r + c] = A.a[3*r + 0] * B.a[0 + c]
                         + A.a[3*r + 1] * B.a[3 + c]
                         + A.a[3*r + 2] * B.a[6 + c];
    return C;
}

__device__ __forceinline__ V3 step(const M3& P, V3 pp, int axis, float s) {
    V3 q;
    q.x = pp.x + s * P.a[0 + axis];
    q.y = pp.y + s * P.a[3 + axis];
    q.z = pp.z + s * P.a[6 + axis];
    return q;
}

__device__ __forceinline__ void put(float* so, int j, V3 q) {
    so[3*j + 0] = q.x; so[3*j + 1] = q.y; so[3*j + 2] = q.z;
}

// FK from per-joint register float2 triples -> LDS overlay slice `so`.
// v[u] maps to joints {0,1,2,4,5,7,8,9,11,12,14,15}.
__device__ __forceinline__ void fk_from_regs(const float2 v[12][3], float* so,
                                             const float* len,
                                             float rx, float ry, float rz) {
    V3 q0; q0.x = rx; q0.y = ry; q0.z = rz;
    so[0] = rx; so[1] = ry; so[2] = rz;
    M3 W0 = rot6d2(v[0]);

    M3 W1 = m3mul(W0, rot6d2(v[1]));  V3 q1 = step(W0, q0, 0, -len[0]);  put(so, 1, q1);
    M3 W2 = m3mul(W1, rot6d2(v[2]));  V3 q2 = step(W1, q1, 1, -len[1]);  put(so, 2, q2);
    /* leaf 3 */                      V3 q3 = step(W2, q2, 1, -len[2]);  put(so, 3, q3);

    M3 W4 = m3mul(W0, rot6d2(v[3]));  V3 q4 = step(W0, q0, 0,  len[3]);  put(so, 4, q4);
    M3 W5 = m3mul(W4, rot6d2(v[4]));  V3 q5 = step(W4, q4, 1, -len[4]);  put(so, 5, q5);
    /* leaf 6 */                      V3 q6 = step(W5, q5, 1, -len[5]);  put(so, 6, q6);

    M3 W7 = m3mul(W0, rot6d2(v[5]));  V3 q7 = step(W0, q0, 1,  len[6]);  put(so, 7, q7);
    M3 W8 = m3mul(W7, rot6d2(v[6]));  V3 q8 = step(W7, q7, 1,  len[7]);  put(so, 8, q8);

    M3 W9 = m3mul(W8, rot6d2(v[7]));  V3 q9 = step(W8, q8, 1,  len[8]);  put(so, 9, q9);
    /* leaf 10 */                     V3 q10 = step(W9, q9, 1, len[9]);  put(so, 10, q10);

    M3 W11 = m3mul(W8,  rot6d2(v[8]));  V3 q11 = step(W8,  q8,  0, len[10]); put(so, 11, q11);
    M3 W12 = m3mul(W11, rot6d2(v[9]));  V3 q12 = step(W11, q11, 0, len[11]); put(so, 12, q12);
    /* leaf 13 */                       V3 q13 = step(W12, q12, 0, len[12]); put(so, 13, q13);

    M3 W14 = m3mul(W8,  rot6d2(v[10])); V3 q14 = step(W8,  q8,  0, -len[13]); put(so, 14, q14);
    M3 W15 = m3mul(W14, rot6d2(v[11])); V3 q15 = step(W14, q14, 0, -len[14]); put(so, 15, q15);
    /* leaf 16 */                       V3 q16 = step(W15, q15, 0, -len[15]); put(so, 16, q16);
}

__device__ __forceinline__ void load_sample(const float* __restrict__ rot,
                                            long long gs, float2 v[12][3]) {
    constexpr int UJ[12] = {0, 1, 2, 4, 5, 7, 8, 9, 11, 12, 14, 15};
    const float2* g2 = (const float2*)(rot + (size_t)gs * 102);   // 8B-aligned
#pragma unroll
    for (int u = 0; u < 12; ++u)
#pragma unroll
        for (int k = 0; k < 3; ++k)
            v[u][k] = g2[UJ[u] * 3 + k];
}

__global__ __launch_bounds__(TPB) void PoseDecoder_kernel(
    const float* __restrict__ rot,    // [BL,17,6]
    const float* __restrict__ bones,  // [B,16]
    const float* __restrict__ root,   // [BL,3]
    float* __restrict__ out,          // [BL,17,3]
    int BL, int L)
{
    __shared__ __align__(16) float s_in[TPB * 102];   // 26112 B: tile-B DMA image
    __shared__ __align__(16) float s_out[TPB * 51];   // 13056 B: output overlay
    const int t = threadIdx.x;
    const long long blk_base = (long long)blockIdx.x * 128;

    const bool fast = (blk_base + 128 <= BL) &&
                      (blk_base / L == (blk_base + 127) / L);

    if (fast) {
        const long long gsA = blk_base + t, gsB = blk_base + 64 + t;

        // ---- phase 1a: tile A scattered loads straight to VGPRs (oldest in
        //      FIFO: waiting on these does NOT drain the DMA queue behind) ----
        float2 vA[12][3];
        load_sample(rot, gsA, vA);
        float rAx = root[gsA*3+0], rAy = root[gsA*3+1], rAz = root[gsA*3+2];
        float rBx = root[gsB*3+0], rBy = root[gsB*3+1], rBz = root[gsB*3+2];

        // pin issue order: A reg-loads (+roots) BEFORE the DMA batch
        __builtin_amdgcn_sched_barrier(0);

        // ---- phase 1b: tile B -> LDS via DMA, zero VGPR cost, 27 ops ----
        {
            const char* gb = (const char*)rot + (size_t)(blk_base + 64) * 408;
#pragma unroll
            for (int r = 0; r < 25; ++r)
                __builtin_amdgcn_global_load_lds(
                    (g_void*)(gb + r * 1024 + t * 16),
                    (lds_void*)((char*)s_in + r * 1024), 16, 0, 0);
            __builtin_amdgcn_global_load_lds((g_void*)(gb + 25600 + t * 4),
                    (lds_void*)((char*)s_in + 25600), 4, 0, 0);
            __builtin_amdgcn_global_load_lds((g_void*)(gb + 25856 + t * 4),
                    (lds_void*)((char*)s_in + 25856), 4, 0, 0);
        }

        // bones: one group per 128-sample block (L multiple of 128) -> SGPRs
        const float* bl = bones + (size_t)(blk_base / L) * 16;
        float len[16];
#pragma unroll
        for (int k = 0; k < 16; ++k) len[k] = bl[k];

        // ---- phase 2: FK(A) from regs (B's 26 KB in flight underneath) ----
        fk_from_regs(vA, s_out + t * 51, len, rAx, rAy, rAz);
        fence_lgkm();                   // overlay complete

        // ---- phase 3: coalesced store A ----
        {
            float4* o4 = (float4*)(out + (size_t)blk_base * 51);
            const float4* l4 = (const float4*)s_out;
#pragma unroll
            for (int r = 0; r < 12; ++r) o4[r * 64 + t] = l4[r * 64 + t];
            if (t < 48) o4[768 + t] = l4[768 + t];
        }

        // ---- phase 4: drain DMA (landed during FK(A)) + overlay ds_reads ----
        asm volatile("s_waitcnt vmcnt(0) lgkmcnt(0)" ::: "memory");
        __builtin_amdgcn_wave_barrier();

        // ---- phase 5: tile B from LDS -> regs, FK(B), store ----
        float2 vB[12][3];
        {
            constexpr int UJ[12] = {0, 1, 2, 4, 5, 7, 8, 9, 11, 12, 14, 15};
            const float2* l2 = (const float2*)(s_in + t * 102);
#pragma unroll
            for (int u = 0; u < 12; ++u)
#pragma unroll
                for (int k = 0; k < 3; ++k)
                    vB[u][k] = l2[UJ[u] * 3 + k];
        }
        fk_from_regs(vB, s_out + t * 51, len, rBx, rBy, rBz);
        fence_lgkm();
        {
            float4* o4 = (float4*)(out + (size_t)(blk_base + 64) * 51);
            const float4* l4 = (const float4*)s_out;
#pragma unroll
            for (int r = 0; r < 12; ++r) o4[r * 64 + t] = l4[r * 64 + t];
            if (t < 48) o4[768 + t] = l4[768 + t];
        }
    } else {
        // generic fallback (partial block / bone-boundary crossing)
        for (int half = 0; half < 2; ++half) {
            const long long gs = blk_base + half * 64 + t;
            if (gs >= BL) break;
            float2 v[12][3];
            load_sample(rot, gs, v);
            float rx = root[gs*3+0], ry = root[gs*3+1], rz = root[gs*3+2];
            const float* bl = bones + (size_t)(gs / L) * 16;
            float len[16];
#pragma unroll
            for (int k = 0; k < 16; ++k) len[k] = bl[k];
            float so[51];
            fk_from_regs(v, so, len, rx, ry, rz);
            for (int m = 0; m < 51; ++m) out[gs * 51 + m] = so[m];  // slow, correct
        }
    }
}

extern "C" void kernel_launch(void* const* d_in, const int* in_sizes, int n_in,
                              void* d_out, int out_size, void* d_ws, size_t ws_size,
                              hipStream_t stream) {
    const float* rot   = (const float*)d_in[0];
    const float* bones = (const float*)d_in[1];
    const float* root  = (const float*)d_in[2];
    float* out = (float*)d_out;

    int BL = in_sizes[0] / 102;     // 17 joints * 6
    int B  = in_sizes[1] / 16;      // 16 bones
    int L  = BL / B;

    int grid = (BL + 127) / 128;
    PoseDecoder_kernel<<<grid, TPB, 0, stream>>>(rot, bones, root, out, BL, L);
}